// Round 4
// baseline (248.687 us; speedup 1.0000x reference)
//
#include <hip/hip_runtime.h>
#include <hip/hip_bf16.h>

#define L_SEQ 65536
#define TILE 64
#define TILES_PER_B 1024

typedef __attribute__((ext_vector_type(8))) short bf16x8;
typedef __attribute__((ext_vector_type(4))) short s16x4;
typedef __attribute__((ext_vector_type(4))) float f32x4;

// workspace layout (bytes)
#define WS_WFX   0        // bf16 [3][64][64] : WfT_s[d][c] = (W_in@W_ip_x)^T[d][c] * conv_w[d][s]
#define WS_W1R   24576    // bf16 [64][64]    : W1rT[d][c]  (res half of in_proj, transposed)
#define WS_W2T   32768    // bf16 [64][64]    : W2T[c'][d] = (W_op@W_out)^T
#define WS_WG2T  40960    // bf16 [64][16]    : Wg2T[c][j] = W_g2[j][c]
#define WS_BX    43008    // f32 [64] : b1x*(w0+w1+w2) + conv_b   (interior conv bias)
#define WS_BR    43264    // f32 [64] : b1 res half
#define WS_BC0   43520    // f32 [64] : b1x*w0  (subtract at global row 0)
#define WS_BC2   43776    // f32 [64] : b1x*w2  (subtract at global row L-1)
#define WS_B2    44032    // f32 [64]

__device__ __forceinline__ short f2bf(float f) {
    __bf16 h = (__bf16)f;
    return __builtin_bit_cast(short, h);
}
__device__ __forceinline__ float fsigmoid(float x) {
    return __builtin_amdgcn_rcpf(1.0f + __builtin_amdgcn_exp2f(-1.44269504089f * x));
}

__device__ __forceinline__ bf16x8 ldcvt(const float* __restrict__ p) {
    float4 a = *(const float4*)p;
    float4 b = *(const float4*)(p + 4);
    bf16x8 f;
    f[0]=f2bf(a.x); f[1]=f2bf(a.y); f[2]=f2bf(a.z); f[3]=f2bf(a.w);
    f[4]=f2bf(b.x); f[5]=f2bf(b.y); f[6]=f2bf(b.z); f[7]=f2bf(b.w);
    return f;
}

// ---------------- prep: compose + conv-fold weights ----------------
__global__ void prep_kernel(const float* __restrict__ W_in, const float* __restrict__ b_in,
                            const float* __restrict__ W_ip, const float* __restrict__ b_ip,
                            const float* __restrict__ conv_w, const float* __restrict__ conv_b,
                            const float* __restrict__ W_op, const float* __restrict__ b_op,
                            const float* __restrict__ W_g2,
                            const float* __restrict__ W_out, const float* __restrict__ b_out,
                            void* __restrict__ ws)
{
    short* wfx  = (short*)((char*)ws + WS_WFX);
    short* w1r  = (short*)((char*)ws + WS_W1R);
    short* w2t  = (short*)((char*)ws + WS_W2T);
    short* wg2t = (short*)((char*)ws + WS_WG2T);
    float* bx   = (float*)((char*)ws + WS_BX);
    float* br   = (float*)((char*)ws + WS_BR);
    float* bc0  = (float*)((char*)ws + WS_BC0);
    float* bc2  = (float*)((char*)ws + WS_BC2);
    float* b2   = (float*)((char*)ws + WS_B2);

    int tid = blockIdx.x * blockDim.x + threadIdx.x;
    if (tid < 12288) {                      // WfT_s[d][c], folded conv
        int s = tid >> 12, rem = tid & 4095;
        int d = rem >> 6, c = rem & 63;
        float acc = 0.f;
        for (int e = 0; e < 64; ++e) acc += W_in[c*64 + e] * W_ip[e*128 + d];
        wfx[(s*64 + d)*64 + c] = f2bf(acc * conv_w[3*d + s]);
    } else if (tid < 16384) {               // W1rT[d][c]
        int rem = tid - 12288; int d = rem >> 6, c = rem & 63;
        float acc = 0.f;
        for (int e = 0; e < 64; ++e) acc += W_in[c*64 + e] * W_ip[e*128 + 64 + d];
        w1r[d*64 + c] = f2bf(acc);
    } else if (tid < 20480) {               // W2T[c'][d]
        int rem = tid - 16384; int cp = rem >> 6, d = rem & 63;
        float acc = 0.f;
        for (int e = 0; e < 64; ++e) acc += W_op[d*64 + e] * W_out[e*64 + cp];
        w2t[cp*64 + d] = f2bf(acc);
    } else if (tid < 21504) {               // Wg2T[c][j]
        int rem = tid - 20480; int c = rem >> 4, j = rem & 15;
        wg2t[c*16 + j] = f2bf(W_g2[j*64 + c]);
    } else if (tid < 21568) {               // bx[d]
        int d = tid - 21504;
        float b1x = b_ip[d];
        for (int e = 0; e < 64; ++e) b1x += b_in[e] * W_ip[e*128 + d];
        bx[d] = b1x * (conv_w[3*d] + conv_w[3*d+1] + conv_w[3*d+2]) + conv_b[d];
    } else if (tid < 21632) {               // br[d]
        int d = tid - 21568;
        float s = b_ip[64 + d];
        for (int e = 0; e < 64; ++e) s += b_in[e] * W_ip[e*128 + 64 + d];
        br[d] = s;
    } else if (tid < 21696) {               // bc0[d]
        int d = tid - 21632;
        float b1x = b_ip[d];
        for (int e = 0; e < 64; ++e) b1x += b_in[e] * W_ip[e*128 + d];
        bc0[d] = b1x * conv_w[3*d];
    } else if (tid < 21760) {               // bc2[d]
        int d = tid - 21696;
        float b1x = b_ip[d];
        for (int e = 0; e < 64; ++e) b1x += b_in[e] * W_ip[e*128 + d];
        bc2[d] = b1x * conv_w[3*d + 2];
    } else if (tid < 21824) {               // b2[c']
        int cp = tid - 21760;
        float s = b_out[cp];
        for (int e = 0; e < 64; ++e) s += b_op[e] * W_out[e*64 + cp];
        b2[cp] = s;
    }
}

// ---------------- fused main kernel: conv folded into GEMM1, 1 barrier ----------------
// LDS = 9216 (O) + 2048 (hl) = 11264 B
__global__ __launch_bounds__(256, 6) void fgs_main(
    const float* __restrict__ x, const float* __restrict__ freq,
    const float* __restrict__ wg1, const float* __restrict__ bg1,
    const float* __restrict__ bg2,
    const void* __restrict__ ws, float* __restrict__ out)
{
    const short* wfx  = (const short*)((const char*)ws + WS_WFX);
    const short* w1r  = (const short*)((const char*)ws + WS_W1R);
    const short* w2t  = (const short*)((const char*)ws + WS_W2T);
    const short* wg2t = (const short*)((const char*)ws + WS_WG2T);
    const float* bxv  = (const float*)((const char*)ws + WS_BX);
    const float* brv  = (const float*)((const char*)ws + WS_BR);
    const float* bc0  = (const float*)((const char*)ws + WS_BC0);
    const float* bc2  = (const float*)((const char*)ws + WS_BC2);
    const float* b2   = (const float*)((const char*)ws + WS_B2);

    __shared__ short ot[64][72];   // O = silu(conv_x)*silu(res), bf16
    __shared__ short hl[64][16];   // H = relu(f*Wg1+bg1)

    const int bid   = blockIdx.x;
    const int batch = bid >> 10;
    const int tile  = bid & 1023;
    const int base  = tile << 6;
    const bool edge = (tile == 0) || (tile == 1023);

    const int lane = threadIdx.x & 63;
    const int w    = threadIdx.x >> 6;   // wave 0..3
    const int lr   = lane & 15;
    const int g    = lane >> 4;
    const int r    = 16*w + lr;

    const size_t brow0 = (size_t)batch * L_SEQ;

    // ---- gate hidden H (pre-barrier; hides under GEMM1) ----
    if (g < 2) {
        float f = freq[brow0 + base + r];
        float4 wa = *(const float4*)(wg1 + 8*g);
        float4 wb = *(const float4*)(wg1 + 8*g + 4);
        float4 ba = *(const float4*)(bg1 + 8*g);
        float4 bb = *(const float4*)(bg1 + 8*g + 4);
        bf16x8 hv;
        hv[0] = f2bf(fmaxf(f*wa.x + ba.x, 0.f));
        hv[1] = f2bf(fmaxf(f*wa.y + ba.y, 0.f));
        hv[2] = f2bf(fmaxf(f*wa.z + ba.z, 0.f));
        hv[3] = f2bf(fmaxf(f*wa.w + ba.w, 0.f));
        hv[4] = f2bf(fmaxf(f*wb.x + bb.x, 0.f));
        hv[5] = f2bf(fmaxf(f*wb.y + bb.y, 0.f));
        hv[6] = f2bf(fmaxf(f*wb.z + bb.z, 0.f));
        hv[7] = f2bf(fmaxf(f*wb.w + bb.w, 0.f));
        *(bf16x8*)&hl[r][8*g] = hv;
    }

    // ---- GEMM1 (conv-folded, transposed): accx = conv(x@W1x), accr = x@W1r ----
    f32x4 accx[4] = {};
    f32x4 accr[4] = {};

    if (!edge) {
        const float* xp0 = x + (brow0 + (size_t)(base + lr)) * 64 + 8*g;
        #pragma unroll
        for (int kk = 0; kk < 2; ++kk) {
            #pragma unroll
            for (int s = 0; s < 3; ++s) {
                bf16x8 a = *(const bf16x8*)(wfx + (s*64 + 16*w + lr)*64 + 32*kk + 8*g);
                bf16x8 bfr[4];
                #pragma unroll
                for (int nt = 0; nt < 4; ++nt)
                    bfr[nt] = ldcvt(xp0 + (size_t)(16*nt + s - 1)*64 + 32*kk);
                #pragma unroll
                for (int nt = 0; nt < 4; ++nt)
                    accx[nt] = __builtin_amdgcn_mfma_f32_16x16x32_bf16(a, bfr[nt], accx[nt], 0, 0, 0);
                if (s == 1) {
                    bf16x8 ar = *(const bf16x8*)(w1r + (16*w + lr)*64 + 32*kk + 8*g);
                    #pragma unroll
                    for (int nt = 0; nt < 4; ++nt)
                        accr[nt] = __builtin_amdgcn_mfma_f32_16x16x32_bf16(ar, bfr[nt], accr[nt], 0, 0, 0);
                }
            }
        }
    } else {
        #pragma unroll
        for (int kk = 0; kk < 2; ++kk) {
            #pragma unroll
            for (int s = 0; s < 3; ++s) {
                bf16x8 a = *(const bf16x8*)(wfx + (s*64 + 16*w + lr)*64 + 32*kk + 8*g);
                bf16x8 bfr[4];
                #pragma unroll
                for (int nt = 0; nt < 4; ++nt) {
                    int grow = base + 16*nt + lr + s - 1;
                    bool v = ((unsigned)grow < (unsigned)L_SEQ);
                    const float* p = x + (brow0 + (size_t)(v ? grow : 0)) * 64 + 32*kk + 8*g;
                    bf16x8 f = ldcvt(p);
                    if (!v) { bf16x8 z = {}; f = z; }
                    bfr[nt] = f;
                }
                #pragma unroll
                for (int nt = 0; nt < 4; ++nt)
                    accx[nt] = __builtin_amdgcn_mfma_f32_16x16x32_bf16(a, bfr[nt], accx[nt], 0, 0, 0);
                if (s == 1) {
                    bf16x8 ar = *(const bf16x8*)(w1r + (16*w + lr)*64 + 32*kk + 8*g);
                    #pragma unroll
                    for (int nt = 0; nt < 4; ++nt)
                        accr[nt] = __builtin_amdgcn_mfma_f32_16x16x32_bf16(ar, bfr[nt], accr[nt], 0, 0, 0);
                }
            }
        }
    }

    // ---- epilogue 1: o = silu(x_conv)*silu(res) in-register -> LDS ----
    {
        const int c0 = 16*w + 4*g;       // d column base (0..63); same lane holds d and d+64
        float4 bbx = *(const float4*)(bxv + c0);
        float4 bbr = *(const float4*)(brv + c0);
        #pragma unroll
        for (int nt = 0; nt < 4; ++nt) {
            int trow = 16*nt + lr;
            f32x4 vx = accx[nt];
            f32x4 vr = accr[nt];
            vx[0] += bbx.x; vx[1] += bbx.y; vx[2] += bbx.z; vx[3] += bbx.w;
            vr[0] += bbr.x; vr[1] += bbr.y; vr[2] += bbr.z; vr[3] += bbr.w;
            if (edge) {
                int grow = base + trow;
                if (grow == 0) {
                    float4 c = *(const float4*)(bc0 + c0);
                    vx[0] -= c.x; vx[1] -= c.y; vx[2] -= c.z; vx[3] -= c.w;
                }
                if (grow == L_SEQ - 1) {
                    float4 c = *(const float4*)(bc2 + c0);
                    vx[0] -= c.x; vx[1] -= c.y; vx[2] -= c.z; vx[3] -= c.w;
                }
            }
            s16x4 pv;
            #pragma unroll
            for (int j = 0; j < 4; ++j) {
                float xx = vx[j], rr = vr[j];
                float ex = __builtin_amdgcn_exp2f(-1.44269504089f * xx);
                float er = __builtin_amdgcn_exp2f(-1.44269504089f * rr);
                float o = xx * rr * __builtin_amdgcn_rcpf((1.0f + ex) * (1.0f + er));
                pv[j] = f2bf(o);
            }
            *(s16x4*)&ot[trow][c0] = pv;
        }
    }
    __syncthreads();

    // ---- GEMM2: Y^T = W2T @ O^T ; gate: Wg2T @ H^T ----
    f32x4 acc2[4] = {};
    {
        bf16x8 a2_0 = *(const bf16x8*)(w2t + (16*w + lr)*64 + 8*g);
        bf16x8 a2_1 = *(const bf16x8*)(w2t + (16*w + lr)*64 + 32 + 8*g);
        #pragma unroll
        for (int nt = 0; nt < 4; ++nt) {
            int row = 16*nt + lr;
            bf16x8 bo0 = *(bf16x8*)&ot[row][8*g];
            bf16x8 bo1 = *(bf16x8*)&ot[row][32 + 8*g];
            acc2[nt] = __builtin_amdgcn_mfma_f32_16x16x32_bf16(a2_0, bo0, acc2[nt], 0, 0, 0);
            acc2[nt] = __builtin_amdgcn_mfma_f32_16x16x32_bf16(a2_1, bo1, acc2[nt], 0, 0, 0);
        }
    }
    f32x4 accg[4] = {};
    {
        bf16x8 zf = {};
        bf16x8 ag = (g < 2) ? *(const bf16x8*)(wg2t + (16*w + lr)*16 + 8*g) : zf;
        #pragma unroll
        for (int nt = 0; nt < 4; ++nt) {
            bf16x8 bh = (g < 2) ? *(bf16x8*)&hl[16*nt + lr][8*g] : zf;
            accg[nt] = __builtin_amdgcn_mfma_f32_16x16x32_bf16(ag, bh, accg[nt], 0, 0, 0);
        }
    }

    // ---- epilogue 2: y = (Y + b2) * sigmoid(G + bg2), unmasked float4 stores ----
    {
        const int c0 = 16*w + 4*g;
        float4 bb2 = *(const float4*)(b2 + c0);
        float4 bbg = *(const float4*)(bg2 + c0);
        float* op0 = out + (brow0 + (size_t)(base + lr)) * 64 + c0;
        #pragma unroll
        for (int nt = 0; nt < 4; ++nt) {
            f32x4 y = acc2[nt], gg = accg[nt];
            float4 o;
            o.x = (y[0] + bb2.x) * fsigmoid(gg[0] + bbg.x);
            o.y = (y[1] + bb2.y) * fsigmoid(gg[1] + bbg.y);
            o.z = (y[2] + bb2.z) * fsigmoid(gg[2] + bbg.z);
            o.w = (y[3] + bb2.w) * fsigmoid(gg[3] + bbg.w);
            *(float4*)(op0 + (size_t)(16*nt)*64) = o;
        }
    }
}

extern "C" void kernel_launch(void* const* d_in, const int* in_sizes, int n_in,
                              void* d_out, int out_size, void* d_ws, size_t ws_size,
                              hipStream_t stream)
{
    const float* x      = (const float*)d_in[0];
    const float* freq   = (const float*)d_in[1];
    const float* W_in   = (const float*)d_in[2];
    const float* b_in   = (const float*)d_in[3];
    const float* W_ip   = (const float*)d_in[4];
    const float* b_ip   = (const float*)d_in[5];
    const float* conv_w = (const float*)d_in[6];
    const float* conv_b = (const float*)d_in[7];
    const float* W_op   = (const float*)d_in[8];
    const float* b_op   = (const float*)d_in[9];
    const float* W_g1   = (const float*)d_in[10];
    const float* b_g1   = (const float*)d_in[11];
    const float* W_g2   = (const float*)d_in[12];
    const float* b_g2   = (const float*)d_in[13];
    const float* W_out  = (const float*)d_in[14];
    const float* b_out  = (const float*)d_in[15];
    float* out = (float*)d_out;

    prep_kernel<<<86, 256, 0, stream>>>(W_in, b_in, W_ip, b_ip, conv_w, conv_b,
                                        W_op, b_op, W_g2, W_out, b_out, d_ws);
    fgs_main<<<8 * TILES_PER_B, 256, 0, stream>>>(x, freq, W_g1, b_g1, b_g2, d_ws, out);
}

// Round 5
// 86.530 us; speedup vs baseline: 2.8740x; 2.8740x over previous
//
#include <hip/hip_runtime.h>
#include <hip/hip_bf16.h>

#define L_SEQ 65536
#define TILE 64
#define TILES_PER_B 1024

typedef __attribute__((ext_vector_type(8))) short bf16x8;
typedef __attribute__((ext_vector_type(4))) short s16x4;
typedef __attribute__((ext_vector_type(4))) float f32x4;

// workspace layout (bytes)
#define WS_WFX   0        // bf16 [3][64][64] : WfT_s[d][c] = (W_in@W_ip_x)^T[d][c] * conv_w[d][s]
#define WS_W1R   24576    // bf16 [64][64]    : W1rT[d][c]  (res half of in_proj, transposed)
#define WS_W2T   32768    // bf16 [64][64]    : W2T[c'][d] = (W_op@W_out)^T
#define WS_WG2T  40960    // bf16 [64][16]    : Wg2T[c][j] = W_g2[j][c]
#define WS_BX    43008    // f32 [64] : b1x*(w0+w1+w2) + conv_b   (interior conv bias)
#define WS_BR    43264    // f32 [64] : b1 res half
#define WS_BC0   43520    // f32 [64] : b1x*w0  (subtract at global row 0)
#define WS_BC2   43776    // f32 [64] : b1x*w2  (subtract at global row L-1)
#define WS_B2    44032    // f32 [64]

__device__ __forceinline__ short f2bf(float f) {
    __bf16 h = (__bf16)f;
    return __builtin_bit_cast(short, h);
}
__device__ __forceinline__ float fsigmoid(float x) {
    return __builtin_amdgcn_rcpf(1.0f + __builtin_amdgcn_exp2f(-1.44269504089f * x));
}

// ---------------- prep: compose + conv-fold weights ----------------
__global__ void prep_kernel(const float* __restrict__ W_in, const float* __restrict__ b_in,
                            const float* __restrict__ W_ip, const float* __restrict__ b_ip,
                            const float* __restrict__ conv_w, const float* __restrict__ conv_b,
                            const float* __restrict__ W_op, const float* __restrict__ b_op,
                            const float* __restrict__ W_g2,
                            const float* __restrict__ W_out, const float* __restrict__ b_out,
                            void* __restrict__ ws)
{
    short* wfx  = (short*)((char*)ws + WS_WFX);
    short* w1r  = (short*)((char*)ws + WS_W1R);
    short* w2t  = (short*)((char*)ws + WS_W2T);
    short* wg2t = (short*)((char*)ws + WS_WG2T);
    float* bx   = (float*)((char*)ws + WS_BX);
    float* br   = (float*)((char*)ws + WS_BR);
    float* bc0  = (float*)((char*)ws + WS_BC0);
    float* bc2  = (float*)((char*)ws + WS_BC2);
    float* b2   = (float*)((char*)ws + WS_B2);

    int tid = blockIdx.x * blockDim.x + threadIdx.x;
    if (tid < 12288) {                      // WfT_s[d][c], folded conv
        int s = tid >> 12, rem = tid & 4095;
        int d = rem >> 6, c = rem & 63;
        float acc = 0.f;
        for (int e = 0; e < 64; ++e) acc += W_in[c*64 + e] * W_ip[e*128 + d];
        wfx[(s*64 + d)*64 + c] = f2bf(acc * conv_w[3*d + s]);
    } else if (tid < 16384) {               // W1rT[d][c]
        int rem = tid - 12288; int d = rem >> 6, c = rem & 63;
        float acc = 0.f;
        for (int e = 0; e < 64; ++e) acc += W_in[c*64 + e] * W_ip[e*128 + 64 + d];
        w1r[d*64 + c] = f2bf(acc);
    } else if (tid < 20480) {               // W2T[c'][d]
        int rem = tid - 16384; int cp = rem >> 6, d = rem & 63;
        float acc = 0.f;
        for (int e = 0; e < 64; ++e) acc += W_op[d*64 + e] * W_out[e*64 + cp];
        w2t[cp*64 + d] = f2bf(acc);
    } else if (tid < 21504) {               // Wg2T[c][j]
        int rem = tid - 20480; int c = rem >> 4, j = rem & 15;
        wg2t[c*16 + j] = f2bf(W_g2[j*64 + c]);
    } else if (tid < 21568) {               // bx[d]
        int d = tid - 21504;
        float b1x = b_ip[d];
        for (int e = 0; e < 64; ++e) b1x += b_in[e] * W_ip[e*128 + d];
        bx[d] = b1x * (conv_w[3*d] + conv_w[3*d+1] + conv_w[3*d+2]) + conv_b[d];
    } else if (tid < 21632) {               // br[d]
        int d = tid - 21568;
        float s = b_ip[64 + d];
        for (int e = 0; e < 64; ++e) s += b_in[e] * W_ip[e*128 + 64 + d];
        br[d] = s;
    } else if (tid < 21696) {               // bc0[d]
        int d = tid - 21632;
        float b1x = b_ip[d];
        for (int e = 0; e < 64; ++e) b1x += b_in[e] * W_ip[e*128 + d];
        bc0[d] = b1x * conv_w[3*d];
    } else if (tid < 21760) {               // bc2[d]
        int d = tid - 21696;
        float b1x = b_ip[d];
        for (int e = 0; e < 64; ++e) b1x += b_in[e] * W_ip[e*128 + d];
        bc2[d] = b1x * conv_w[3*d + 2];
    } else if (tid < 21824) {               // b2[c']
        int cp = tid - 21760;
        float s = b_out[cp];
        for (int e = 0; e < 64; ++e) s += b_op[e] * W_out[e*64 + cp];
        b2[cp] = s;
    }
}

// ---------------- fused main kernel: conv-fold + LDS-staged x ----------------
// LDS = 8448 (xs) + 9216 (ot) + 2048 (hl) = 19712 B -> 8 blocks/CU by LDS
__global__ __launch_bounds__(256, 6) void fgs_main(
    const float* __restrict__ x, const float* __restrict__ freq,
    const float* __restrict__ wg1, const float* __restrict__ bg1,
    const float* __restrict__ bg2,
    const void* __restrict__ ws, float* __restrict__ out)
{
    const short* wfx  = (const short*)((const char*)ws + WS_WFX);
    const short* w1r  = (const short*)((const char*)ws + WS_W1R);
    const short* w2t  = (const short*)((const char*)ws + WS_W2T);
    const short* wg2t = (const short*)((const char*)ws + WS_WG2T);
    const float* bxv  = (const float*)((const char*)ws + WS_BX);
    const float* brv  = (const float*)((const char*)ws + WS_BR);
    const float* bc0  = (const float*)((const char*)ws + WS_BC0);
    const float* bc2  = (const float*)((const char*)ws + WS_BC2);
    const float* b2   = (const float*)((const char*)ws + WS_B2);

    // xs: 66 rows x 64 bf16 (row = global row base-1+i), row stride 128B,
    // 16B-chunk swizzle: chunk' = chunk ^ (row & 7)  -> conflict-free frag reads
    __shared__ short xs[66 * 64];
    __shared__ short ot[64][72];   // O = silu(conv_x)*silu(res), bf16
    __shared__ short hl[64][16];   // H = relu(f*Wg1+bg1)

    const int bid   = blockIdx.x;
    const int batch = bid >> 10;
    const int tile  = bid & 1023;
    const int base  = tile << 6;
    const bool edge = (tile == 0) || (tile == 1023);

    const int lane = threadIdx.x & 63;
    const int w    = threadIdx.x >> 6;   // wave 0..3
    const int lr   = lane & 15;
    const int g    = lane >> 4;
    const int r    = 16*w + lr;

    const size_t brow0 = (size_t)batch * L_SEQ;

    // ---- stage x tile (rows base-1 .. base+64) into LDS, bf16, swizzled ----
    {
        auto stage_row = [&](int i, int cf) {   // i: LDS row, cf: f32 col base
            int grow = base - 1 + i;
            bool v = ((unsigned)grow < (unsigned)L_SEQ);
            const float* p = x + (brow0 + (size_t)(v ? grow : 0)) * 64 + cf;
            float4 a = *(const float4*)(p);
            float4 b = *(const float4*)(p + 4);
            float4 c = *(const float4*)(p + 8);
            float4 d = *(const float4*)(p + 12);
            bf16x8 lo, hi;
            lo[0]=f2bf(a.x); lo[1]=f2bf(a.y); lo[2]=f2bf(a.z); lo[3]=f2bf(a.w);
            lo[4]=f2bf(b.x); lo[5]=f2bf(b.y); lo[6]=f2bf(b.z); lo[7]=f2bf(b.w);
            hi[0]=f2bf(c.x); hi[1]=f2bf(c.y); hi[2]=f2bf(c.z); hi[3]=f2bf(c.w);
            hi[4]=f2bf(d.x); hi[5]=f2bf(d.y); hi[6]=f2bf(d.z); hi[7]=f2bf(d.w);
            if (!v) { bf16x8 z = {}; lo = z; hi = z; }
            int c0 = cf >> 3;               // 16B-chunk index
            int sw = i & 7;
            *(bf16x8*)&xs[i*64 + ((c0    ) ^ sw) * 8] = lo;
            *(bf16x8*)&xs[i*64 + ((c0 + 1) ^ sw) * 8] = hi;
        };
        stage_row(threadIdx.x >> 2, (threadIdx.x & 3) * 16);
        if (threadIdx.x < 8)
            stage_row(64 + (threadIdx.x >> 2), (threadIdx.x & 3) * 16);
    }

    // ---- gate hidden H (pre-barrier; hides under stage latency) ----
    if (g < 2) {
        float f = freq[brow0 + base + r];
        float4 wa = *(const float4*)(wg1 + 8*g);
        float4 wb = *(const float4*)(wg1 + 8*g + 4);
        float4 ba = *(const float4*)(bg1 + 8*g);
        float4 bb = *(const float4*)(bg1 + 8*g + 4);
        bf16x8 hv;
        hv[0] = f2bf(fmaxf(f*wa.x + ba.x, 0.f));
        hv[1] = f2bf(fmaxf(f*wa.y + ba.y, 0.f));
        hv[2] = f2bf(fmaxf(f*wa.z + ba.z, 0.f));
        hv[3] = f2bf(fmaxf(f*wa.w + ba.w, 0.f));
        hv[4] = f2bf(fmaxf(f*wb.x + bb.x, 0.f));
        hv[5] = f2bf(fmaxf(f*wb.y + bb.y, 0.f));
        hv[6] = f2bf(fmaxf(f*wb.z + bb.z, 0.f));
        hv[7] = f2bf(fmaxf(f*wb.w + bb.w, 0.f));
        *(bf16x8*)&hl[r][8*g] = hv;
    }
    __syncthreads();

    // ---- GEMM1 (conv-folded): accx = conv(x@W1x), accr = x@W1r ; B-frags from LDS ----
    f32x4 accx[4] = {};
    f32x4 accr[4] = {};
    #pragma unroll
    for (int kk = 0; kk < 2; ++kk) {
        #pragma unroll
        for (int s = 0; s < 3; ++s) {
            bf16x8 a = *(const bf16x8*)(wfx + (s*64 + 16*w + lr)*64 + 32*kk + 8*g);
            int rb = lr + s;                  // LDS row for nt=0 (row base-1+s maps to i=s)
            const short* bp = xs + rb*64 + (((4*kk + g) ^ (rb & 7)) * 8);
            bf16x8 b0 = *(const bf16x8*)(bp);
            bf16x8 b1 = *(const bf16x8*)(bp + 1024);   // +16 rows
            bf16x8 b2f = *(const bf16x8*)(bp + 2048);
            bf16x8 b3 = *(const bf16x8*)(bp + 3072);
            accx[0] = __builtin_amdgcn_mfma_f32_16x16x32_bf16(a, b0, accx[0], 0, 0, 0);
            accx[1] = __builtin_amdgcn_mfma_f32_16x16x32_bf16(a, b1, accx[1], 0, 0, 0);
            accx[2] = __builtin_amdgcn_mfma_f32_16x16x32_bf16(a, b2f, accx[2], 0, 0, 0);
            accx[3] = __builtin_amdgcn_mfma_f32_16x16x32_bf16(a, b3, accx[3], 0, 0, 0);
            if (s == 1) {
                bf16x8 ar = *(const bf16x8*)(w1r + (16*w + lr)*64 + 32*kk + 8*g);
                accr[0] = __builtin_amdgcn_mfma_f32_16x16x32_bf16(ar, b0, accr[0], 0, 0, 0);
                accr[1] = __builtin_amdgcn_mfma_f32_16x16x32_bf16(ar, b1, accr[1], 0, 0, 0);
                accr[2] = __builtin_amdgcn_mfma_f32_16x16x32_bf16(ar, b2f, accr[2], 0, 0, 0);
                accr[3] = __builtin_amdgcn_mfma_f32_16x16x32_bf16(ar, b3, accr[3], 0, 0, 0);
            }
        }
    }

    // ---- epilogue 1: o = silu(x_conv)*silu(res) in-register -> LDS ----
    {
        const int c0 = 16*w + 4*g;       // d column base; same lane holds d and d+64
        float4 bbx = *(const float4*)(bxv + c0);
        float4 bbr = *(const float4*)(brv + c0);
        #pragma unroll
        for (int nt = 0; nt < 4; ++nt) {
            int trow = 16*nt + lr;
            f32x4 vx = accx[nt];
            f32x4 vr = accr[nt];
            vx[0] += bbx.x; vx[1] += bbx.y; vx[2] += bbx.z; vx[3] += bbx.w;
            vr[0] += bbr.x; vr[1] += bbr.y; vr[2] += bbr.z; vr[3] += bbr.w;
            if (edge) {
                int grow = base + trow;
                if (grow == 0) {
                    float4 c = *(const float4*)(bc0 + c0);
                    vx[0] -= c.x; vx[1] -= c.y; vx[2] -= c.z; vx[3] -= c.w;
                }
                if (grow == L_SEQ - 1) {
                    float4 c = *(const float4*)(bc2 + c0);
                    vx[0] -= c.x; vx[1] -= c.y; vx[2] -= c.z; vx[3] -= c.w;
                }
            }
            s16x4 pv;
            #pragma unroll
            for (int j = 0; j < 4; ++j) {
                float xx = vx[j], rr = vr[j];
                float ex = __builtin_amdgcn_exp2f(-1.44269504089f * xx);
                float er = __builtin_amdgcn_exp2f(-1.44269504089f * rr);
                float o = xx * rr * __builtin_amdgcn_rcpf((1.0f + ex) * (1.0f + er));
                pv[j] = f2bf(o);
            }
            *(s16x4*)&ot[trow][c0] = pv;
        }
    }
    __syncthreads();

    // ---- GEMM2: Y^T = W2T @ O^T ; gate: Wg2T @ H^T ----
    f32x4 acc2[4] = {};
    {
        bf16x8 a2_0 = *(const bf16x8*)(w2t + (16*w + lr)*64 + 8*g);
        bf16x8 a2_1 = *(const bf16x8*)(w2t + (16*w + lr)*64 + 32 + 8*g);
        #pragma unroll
        for (int nt = 0; nt < 4; ++nt) {
            int row = 16*nt + lr;
            bf16x8 bo0 = *(bf16x8*)&ot[row][8*g];
            bf16x8 bo1 = *(bf16x8*)&ot[row][32 + 8*g];
            acc2[nt] = __builtin_amdgcn_mfma_f32_16x16x32_bf16(a2_0, bo0, acc2[nt], 0, 0, 0);
            acc2[nt] = __builtin_amdgcn_mfma_f32_16x16x32_bf16(a2_1, bo1, acc2[nt], 0, 0, 0);
        }
    }
    f32x4 accg[4] = {};
    {
        bf16x8 zf = {};
        bf16x8 ag = (g < 2) ? *(const bf16x8*)(wg2t + (16*w + lr)*16 + 8*g) : zf;
        #pragma unroll
        for (int nt = 0; nt < 4; ++nt) {
            bf16x8 bh = (g < 2) ? *(bf16x8*)&hl[16*nt + lr][8*g] : zf;
            accg[nt] = __builtin_amdgcn_mfma_f32_16x16x32_bf16(ag, bh, accg[nt], 0, 0, 0);
        }
    }

    // ---- epilogue 2: y = (Y + b2) * sigmoid(G + bg2), unmasked float4 stores ----
    {
        const int c0 = 16*w + 4*g;
        float4 bb2 = *(const float4*)(b2 + c0);
        float4 bbg = *(const float4*)(bg2 + c0);
        float* op0 = out + (brow0 + (size_t)(base + lr)) * 64 + c0;
        #pragma unroll
        for (int nt = 0; nt < 4; ++nt) {
            f32x4 y = acc2[nt], gg = accg[nt];
            float4 o;
            o.x = (y[0] + bb2.x) * fsigmoid(gg[0] + bbg.x);
            o.y = (y[1] + bb2.y) * fsigmoid(gg[1] + bbg.y);
            o.z = (y[2] + bb2.z) * fsigmoid(gg[2] + bbg.z);
            o.w = (y[3] + bb2.w) * fsigmoid(gg[3] + bbg.w);
            *(float4*)(op0 + (size_t)(16*nt)*64) = o;
        }
    }
}

extern "C" void kernel_launch(void* const* d_in, const int* in_sizes, int n_in,
                              void* d_out, int out_size, void* d_ws, size_t ws_size,
                              hipStream_t stream)
{
    const float* x      = (const float*)d_in[0];
    const float* freq   = (const float*)d_in[1];
    const float* W_in   = (const float*)d_in[2];
    const float* b_in   = (const float*)d_in[3];
    const float* W_ip   = (const float*)d_in[4];
    const float* b_ip   = (const float*)d_in[5];
    const float* conv_w = (const float*)d_in[6];
    const float* conv_b = (const float*)d_in[7];
    const float* W_op   = (const float*)d_in[8];
    const float* b_op   = (const float*)d_in[9];
    const float* W_g1   = (const float*)d_in[10];
    const float* b_g1   = (const float*)d_in[11];
    const float* W_g2   = (const float*)d_in[12];
    const float* b_g2   = (const float*)d_in[13];
    const float* W_out  = (const float*)d_in[14];
    const float* b_out  = (const float*)d_in[15];
    float* out = (float*)d_out;

    prep_kernel<<<86, 256, 0, stream>>>(W_in, b_in, W_ip, b_ip, conv_w, conv_b,
                                        W_op, b_op, W_g2, W_out, b_out, d_ws);
    fgs_main<<<8 * TILES_PER_B, 256, 0, stream>>>(x, freq, W_g1, b_g1, b_g2, d_ws, out);
}